// Round 12
// baseline (225.519 us; speedup 1.0000x reference)
//
#include <hip/hip_runtime.h>

// ---- problem constants ----
#define Bb_ 2
#define S_ 2048
#define D_ 512
#define H_ 8
#define DH_ 64

typedef __attribute__((ext_vector_type(8))) __bf16 bf16x8;
typedef __attribute__((ext_vector_type(4))) __bf16 bf16x4;
typedef __attribute__((ext_vector_type(2))) __bf16 bf16x2;
typedef __attribute__((ext_vector_type(4))) float f32x4;
typedef __attribute__((ext_vector_type(8))) short short8;
typedef __attribute__((ext_vector_type(4))) unsigned u32x4;
typedef __attribute__((ext_vector_type(2))) unsigned u32x2;

// direct global->LDS DMA, 16B per lane; dest = wave-uniform base + lane*16
__device__ __forceinline__ void gload_lds16(const void* g, void* l) {
  __builtin_amdgcn_global_load_lds(
      (const __attribute__((address_space(1))) unsigned int*)g,
      (__attribute__((address_space(3))) unsigned int*)l, 16, 0, 0);
}

// ---------------- merged weight transpose + bf16 convert ----------------
__global__ __launch_bounds__(256) void wtrans_all(
    const float* __restrict__ qvk_w, const float* __restrict__ concat_w,
    const float* __restrict__ mlp1_w, const float* __restrict__ mlp2_w,
    __bf16* __restrict__ qvk_wT, __bf16* __restrict__ concat_wT,
    __bf16* __restrict__ mlp1_wT, __bf16* __restrict__ mlp2_wT) {
  int b = blockIdx.x;
  const float* w;
  __bf16* wt;
  int K, N, idx0;
  if (b < 3072) { w = qvk_w; wt = qvk_wT; K = 512; N = 1536; idx0 = b * 256; }
  else if (b < 4096) { w = concat_w; wt = concat_wT; K = 512; N = 512; idx0 = (b - 3072) * 256; }
  else if (b < 6144) { w = mlp1_w; wt = mlp1_wT; K = 512; N = 1024; idx0 = (b - 4096) * 256; }
  else { w = mlp2_w; wt = mlp2_wT; K = 1024; N = 512; idx0 = (b - 6144) * 256; }
  int idx = idx0 + threadIdx.x;
  int k = idx / N, n = idx - k * N;
  wt[(long)n * K + k] = (__bf16)w[idx];
}

// ---------------- layernorm (ddof=0), row length 512 ----------------
__global__ __launch_bounds__(256) void ln_kernel(const float* __restrict__ x,
                                                 const float* __restrict__ w,
                                                 const float* __restrict__ b,
                                                 __bf16* __restrict__ out) {
  long row = blockIdx.x;
  const float* xr = x + row * 512;
  int t = threadIdx.x;
  float2 v = *reinterpret_cast<const float2*>(xr + t * 2);
  float s = v.x + v.y;
  float sq = v.x * v.x + v.y * v.y;
#pragma unroll
  for (int m = 1; m < 64; m <<= 1) {
    s += __shfl_xor(s, m);
    sq += __shfl_xor(sq, m);
  }
  __shared__ float red[8];
  int wid = t >> 6;
  if ((t & 63) == 0) { red[wid] = s; red[wid + 4] = sq; }
  __syncthreads();
  s = red[0] + red[1] + red[2] + red[3];
  sq = red[4] + red[5] + red[6] + red[7];
  float mu = s * (1.f / 512.f);
  float var = sq * (1.f / 512.f) - mu * mu;
  float rs = rsqrtf(var + 1e-5f);
  int c = t * 2;
  float o0 = (v.x - mu) * rs * w[c] + b[c];
  float o1 = (v.y - mu) * rs * w[c + 1] + b[c + 1];
  bf16x2 ov;
  ov[0] = (__bf16)o0;
  ov[1] = (__bf16)o1;
  *reinterpret_cast<bf16x2*>(out + row * 512 + c) = ov;
}

// ---------------- generic bf16 MFMA GEMM (global_load_lds staging) ----------
template <int ACT, int OUTMODE, bool HASRES>
__global__ __launch_bounds__(256) void gemm_kernel(
    const __bf16* __restrict__ A, const __bf16* __restrict__ Bt,
    const float* __restrict__ bias, const float* __restrict__ res,
    float* __restrict__ outF, __bf16* __restrict__ outB,
    __bf16* __restrict__ outK, __bf16* __restrict__ outVt,
    int lda, int ldb, int ldc, int K) {
  __shared__ __align__(16) __bf16 smem[128 * 128];  // As|Bs in K-loop; Cs after
  __bf16* As = smem;
  __bf16* Bs = smem + 128 * 64;
  int t = threadIdx.x, lane = t & 63, wid = t >> 6;
  const __bf16* Ab = A + (long)blockIdx.y * 128 * lda;
  const __bf16* Bb = Bt + (long)blockIdx.x * 128 * ldb;

  f32x4 acc[4][4];
#pragma unroll
  for (int i = 0; i < 4; i++)
#pragma unroll
    for (int j = 0; j < 4; j++) acc[i][j] = (f32x4){0.f, 0.f, 0.f, 0.f};

  int wr = wid >> 1, wc = wid & 1;
  int kq = lane >> 4;
  int cbase = wid * 256;

  for (int k0 = 0; k0 < K; k0 += 64) {
    __syncthreads();
#pragma unroll
    for (int j = 0; j < 4; j++) {
      int ci = cbase + j * 64 + lane;
      int row = ci >> 3;
      int c = ci & 7;
      int sc = c ^ (row & 7);
      gload_lds16(Ab + (long)row * lda + k0 + sc * 8, &As[(cbase + j * 64) * 8]);
      gload_lds16(Bb + (long)row * ldb + k0 + sc * 8, &Bs[(cbase + j * 64) * 8]);
    }
    __syncthreads();
#pragma unroll
    for (int ks = 0; ks < 2; ks++) {
      bf16x8 af[4], bfr[4];
#pragma unroll
      for (int fm = 0; fm < 4; fm++) {
        int r = wr * 64 + fm * 16 + (lane & 15);
        int c = (ks * 4 + kq) ^ (r & 7);
        af[fm] = *reinterpret_cast<const bf16x8*>(&As[r * 64 + c * 8]);
      }
#pragma unroll
      for (int fn = 0; fn < 4; fn++) {
        int r = wc * 64 + fn * 16 + (lane & 15);
        int c = (ks * 4 + kq) ^ (r & 7);
        bfr[fn] = *reinterpret_cast<const bf16x8*>(&Bs[r * 64 + c * 8]);
      }
#pragma unroll
      for (int fm = 0; fm < 4; fm++)
#pragma unroll
        for (int fn = 0; fn < 4; fn++)
          acc[fm][fn] = __builtin_amdgcn_mfma_f32_16x16x32_bf16(af[fm], bfr[fn],
                                                                acc[fm][fn], 0, 0, 0);
    }
  }

  if (OUTMODE == 2) {
    __syncthreads();
    char* Cb = reinterpret_cast<char*>(smem);
#pragma unroll
    for (int fm = 0; fm < 4; fm++)
#pragma unroll
      for (int fn = 0; fn < 4; fn++) {
        int c = wc * 64 + fn * 16 + (lane & 15);
        int gcol = blockIdx.x * 128 + c;
        float bv = bias[gcol];
#pragma unroll
        for (int r4 = 0; r4 < 4; r4++) {
          int r = wr * 64 + fm * 16 + kq * 4 + r4;
          float v = fmaxf(acc[fm][fn][r4] + bv, 0.f);  // relu
          *reinterpret_cast<__bf16*>(Cb + r * 256 + (((c >> 3) ^ (r & 7)) << 4) +
                                     ((c & 7) << 1)) = (__bf16)v;
        }
      }
    __syncthreads();
    long bbq = (blockIdx.y * 128) >> 11;
    int srow0 = (blockIdx.y * 128) & 2047;
    if (blockIdx.x < 8) {
      int r = t >> 1, half = t & 1;
      int gcol = blockIdx.x * 128 + half * 64;
      __bf16* dst;
      if (gcol < 512)
        dst = outB + ((bbq * 8 + (gcol >> 6)) * 2048 + srow0 + r) * 64;
      else
        dst = outK + ((bbq * 8 + ((gcol - 512) >> 6)) * 2048 + srow0 + r) * 64;
      const char* srcrow = Cb + r * 256;
#pragma unroll
      for (int j = 0; j < 8; j++) {
        bf16x8 vv = *reinterpret_cast<const bf16x8*>(
            srcrow + ((((half * 8 + j) ^ (r & 7))) << 4));
        *reinterpret_cast<bf16x8*>(dst + j * 8) = vv;
      }
    } else {
      int d = t & 63, seg = t >> 6;
      int srow = srow0 + seg * 32;
#pragma unroll
      for (int h2 = 0; h2 < 2; h2++) {
        int c = h2 * 64 + d;
        int h = (blockIdx.x * 128 - 1024 + h2 * 64) >> 6;
        __bf16* dst = outVt + (bbq * 8 + h) * 131072 + (srow >> 5) * 2048 + d * 32;
        bf16x8 wv8[4];
#pragma unroll
        for (int i = 0; i < 32; i++) {
          int r = seg * 32 + i;
          __bf16 val = *reinterpret_cast<const __bf16*>(
              Cb + r * 256 + (((c >> 3) ^ (r & 7)) << 4) + ((c & 7) << 1));
          wv8[i >> 3][i & 7] = val;
        }
#pragma unroll
        for (int i4 = 0; i4 < 4; i4++)
          *reinterpret_cast<bf16x8*>(dst + i4 * 8) = wv8[i4];
      }
    }
    return;
  }

  long gr0 = (long)blockIdx.y * 128 + wr * 64;
  long gc0 = (long)blockIdx.x * 128 + wc * 64;
#pragma unroll
  for (int fm = 0; fm < 4; fm++)
#pragma unroll
    for (int fn = 0; fn < 4; fn++) {
      int col = (int)gc0 + fn * 16 + (lane & 15);
      long rbase = gr0 + fm * 16 + kq * 4;
      float bv = bias ? bias[col] : 0.f;
#pragma unroll
      for (int r4 = 0; r4 < 4; r4++) {
        long grow = rbase + r4;
        float v = acc[fm][fn][r4] + bv;
        if (HASRES) v += res[grow * ldc + col];
        if (ACT == 1) v = fmaxf(v, 0.f);
        if (ACT == 2) v = 0.5f * v * (1.f + erff(v * 0.70710678118f));
        if (OUTMODE == 0) {
          outF[grow * ldc + col] = v;
        } else {
          outB[grow * ldc + col] = (__bf16)v;
        }
      }
    }
}

// ---------------- Gram partials: per (head, 64-k chunk) G-part + kbar-part ----
__global__ __launch_bounds__(256) void gram_kernel(const __bf16* __restrict__ Kh,
                                                   float* __restrict__ gpart,
                                                   float* __restrict__ kpart) {
  int head = blockIdx.x >> 5, chunk = blockIdx.x & 31;
  __shared__ __align__(16) __bf16 kl[64 * 64];
  int t = threadIdx.x;
  const __bf16* src = Kh + ((long)head * 2048 + chunk * 64) * 64;
#pragma unroll
  for (int i = 0; i < 2; i++) {
    int e = (i * 256 + t) * 8;
    *reinterpret_cast<short8*>(&kl[e]) = *reinterpret_cast<const short8*>(&src[e]);
  }
  __syncthreads();
  int d1 = t & 63, g = t >> 6;
  float acc[16];
#pragma unroll
  for (int i = 0; i < 16; i++) acc[i] = 0.f;
  float kb = 0.f;
  for (int r = 0; r < 64; r++) {
    float k1 = (float)kl[r * 64 + d1];
    kb += k1;
    bf16x8 a = *reinterpret_cast<const bf16x8*>(&kl[r * 64 + g * 16]);
    bf16x8 b = *reinterpret_cast<const bf16x8*>(&kl[r * 64 + g * 16 + 8]);
#pragma unroll
    for (int i = 0; i < 8; i++) acc[i] += k1 * (float)a[i];
#pragma unroll
    for (int i = 0; i < 8; i++) acc[8 + i] += k1 * (float)b[i];
  }
  float* gp = gpart + ((long)chunk * 16 + head) * 4096 + d1 * 64 + g * 16;
#pragma unroll
  for (int i = 0; i < 16; i++) gp[i] = acc[i];
  if (g == 0) kpart[(chunk * 16 + head) * 64 + d1] = kb;
}

// ---------------- reduce Gram partials -> G (fp32), kbar ----------------
__global__ __launch_bounds__(256) void greduce_kernel(const float* __restrict__ gpart,
                                                      const float* __restrict__ kpart,
                                                      float* __restrict__ G,
                                                      float* __restrict__ kbar) {
  int idx = blockIdx.x * 256 + threadIdx.x;
  if (idx < 65536) {
    int head = idx >> 12, e = idx & 4095;
    float s = 0.f;
#pragma unroll 4
    for (int c = 0; c < 32; c++) s += gpart[((long)c * 16 + head) * 4096 + e];
    G[idx] = s;
  } else if (idx < 66560) {
    int k = idx - 65536;
    int head = k >> 6, d = k & 63;
    float s = 0.f;
#pragma unroll 4
    for (int c = 0; c < 32; c++) s += kpart[(c * 16 + head) * 64 + d];
    kbar[k] = s * (1.f / 2048.f);
  }
}

// ---------------- per-row stats: mu = q.kbar ; s2 = q^T G q -> (mu, rsqrt) ----
__global__ __launch_bounds__(256, 4) void stats_kernel(const __bf16* __restrict__ Qh,
                                                       const float* __restrict__ G,
                                                       const float* __restrict__ kbar,
                                                       float2* __restrict__ stats) {
  int head = blockIdx.x >> 5, sub = blockIdx.x & 31;
  __shared__ float Gl[4096];
  __shared__ float kbl[64];
  __shared__ __align__(16) float qlf[64 * 68];
  int t = threadIdx.x;
  const float* Gsrc = G + head * 4096;
#pragma unroll
  for (int i = 0; i < 4; i++) {
    int e = (i * 256 + t) * 4;
    *reinterpret_cast<float4*>(&Gl[e]) = *reinterpret_cast<const float4*>(&Gsrc[e]);
  }
  if (t < 16)
    *reinterpret_cast<float4*>(&kbl[t * 4]) =
        *reinterpret_cast<const float4*>(&kbar[head * 64 + t * 4]);
  const __bf16* qsrc = Qh + ((long)head * 2048 + sub * 64) * 64;
#pragma unroll
  for (int i = 0; i < 2; i++) {
    int e = (i * 256 + t) * 8;
    bf16x8 v = *reinterpret_cast<const bf16x8*>(&qsrc[e]);
    int row = e >> 6, col = e & 63;
    float* dst = &qlf[row * 68 + col];
#pragma unroll
    for (int j = 0; j < 8; j++) dst[j] = (float)v[j];
  }
  __syncthreads();
  int qrow = t >> 2, qt = t & 3;
  const float* qr = &qlf[qrow * 68];
  float mup = 0.f, s2p = 0.f;
#pragma unroll
  for (int i = 0; i < 16; i++) {
    int d1 = qt * 16 + i;
    const float* Gr = &Gl[d1 * 64];
    float acc = 0.f;
#pragma unroll
    for (int j = 0; j < 64; j++) acc += Gr[j] * qr[j];
    float q1 = qr[d1];
    s2p += q1 * acc;
    mup += q1 * kbl[d1];
  }
  mup += __shfl_xor(mup, 1); mup += __shfl_xor(mup, 2);
  s2p += __shfl_xor(s2p, 1); s2p += __shfl_xor(s2p, 2);
  if (qt == 0) {
    float mu = mup;
    float var = (s2p - 2048.f * mu * mu) * (1.f / 2047.f);
    stats[(head << 11) + sub * 64 + qrow] = make_float2(mu, rsqrtf(var + 1e-5f));
  }
}

// ---------------- attn7: GEMM-shaped fused attention, dbuf pipeline ----------
// attn6 + double-buffered staging: issue next tile's global_load_lds into the
// other buffer BEFORE computing the current one; ONE vmcnt(0)+barrier per tile
// (T3 "minimum 2-phase": staging latency hides under MFMA+sin).
__global__ __launch_bounds__(256) void attn7_kernel(
    const __bf16* __restrict__ Qh, const __bf16* __restrict__ Kh,
    const __bf16* __restrict__ Vp, const float2* __restrict__ stats,
    float* __restrict__ sco, __bf16* __restrict__ hv) {
  __shared__ __align__(16) __bf16 Ks[2][128 * 64];    // 2 x 16 KB
  __shared__ __align__(16) __bf16 Vs[2][4 * 64 * 32]; // 2 x 16 KB

  int bid = blockIdx.x;                  // 512 blocks
  int xcd = bid & 7, j = bid >> 3;
  int head = xcd * 2 + (j >> 5);         // 2 heads per XCD (K/V L2-resident)
  int qt = j & 31;
  int bb = head >> 3, hh = head & 7;
  int q0 = qt * 64;

  int t = threadIdx.x, lane = t & 63, wv = t >> 6;  // 4 waves
  int cg = lane >> 4, ln = lane & 15;
  int sw7 = ln & 7, sw3 = ln & 3;

  int qrow = q0 + wv * 16 + ln;
  const __bf16* Qr = Qh + ((long)head * 2048 + qrow) * 64;
  bf16x8 qf0 = *reinterpret_cast<const bf16x8*>(Qr + cg * 8);
  bf16x8 qf1 = *reinterpret_cast<const bf16x8*>(Qr + 32 + cg * 8);
  float2 st = stats[(head << 11) + qrow];
  float mu = st.x, rs = st.y;

  const __bf16* Kbase = Kh + (long)head * 131072;
  const __bf16* Vbase = Vp + (long)head * 131072;

  // per-thread staging indices (constant across tiles)
  int ci = wv * 256 + lane;              // base chunk id; +64*jj below
  // K layout: row=ci>>3 (0..127), chunk c=ci&7, source pre-swizzled c^(row&7)
  // V layout: row=ci>>2 (0..255), chunk c=ci&3, source pre-swizzled c^(row&3)

  // ---- pass 1: Z only (dbuf K) ----
  float Z = 0.f;
  {
    // prologue: stage tile 0 -> Ks[0]
#pragma unroll
    for (int jj = 0; jj < 4; jj++) {
      int c2 = ci + jj * 64;
      int row = c2 >> 3, c = c2 & 7, sc = c ^ (row & 7);
      gload_lds16(Kbase + row * 64 + sc * 8, &Ks[0][(wv * 256 + jj * 64) * 8]);
    }
    __syncthreads();
    int cur = 0;
    for (int kt = 0; kt < 16; kt++) {
      if (kt < 15) {
        const __bf16* Kt = Kbase + (kt + 1) * 8192;
#pragma unroll
        for (int jj = 0; jj < 4; jj++) {
          int c2 = ci + jj * 64;
          int row = c2 >> 3, c = c2 & 7, sc = c ^ (row & 7);
          gload_lds16(Kt + row * 64 + sc * 8, &Ks[cur ^ 1][(wv * 256 + jj * 64) * 8]);
        }
      }
      const __bf16* Kcur = Ks[cur];
#pragma unroll
      for (int sl = 0; sl < 8; sl++) {           // 8 slabs of 16 k
        const __bf16* kr = &Kcur[(sl * 16 + ln) * 64];
        bf16x8 a0 = *reinterpret_cast<const bf16x8*>(kr + ((cg ^ sw7) * 8));
        bf16x8 a1 = *reinterpret_cast<const bf16x8*>(kr + (((cg + 4) ^ sw7) * 8));
        f32x4 d = (f32x4){0.f, 0.f, 0.f, 0.f};
        d = __builtin_amdgcn_mfma_f32_16x16x32_bf16(a0, qf0, d, 0, 0, 0);
        d = __builtin_amdgcn_mfma_f32_16x16x32_bf16(a1, qf1, d, 0, 0, 0);
        Z += (1.f + __sinf(1.25f * (d[0] - mu) * rs));
        Z += (1.f + __sinf(1.25f * (d[1] - mu) * rs));
        Z += (1.f + __sinf(1.25f * (d[2] - mu) * rs));
        Z += (1.f + __sinf(1.25f * (d[3] - mu) * rs));
      }
      __syncthreads();  // drains next-tile staging (vmcnt) + guards reuse
      cur ^= 1;
    }
  }
  Z += __shfl_xor(Z, 16);
  Z += __shfl_xor(Z, 32);
  float invZ = 1.f / Z;

  // ---- pass 2: scores + PV (dbuf K+V) ----
  f32x4 hacc[4];
#pragma unroll
  for (int dt = 0; dt < 4; dt++) hacc[dt] = (f32x4){0.f, 0.f, 0.f, 0.f};
  float* srow = sco + ((long)head * 2048 + qrow) * 2048;

  {
    // prologue: stage tile 0 -> buffers[0]
#pragma unroll
    for (int jj = 0; jj < 4; jj++) {
      int c2 = ci + jj * 64;
      int rowk = c2 >> 3, ck = c2 & 7, sck = ck ^ (rowk & 7);
      gload_lds16(Kbase + rowk * 64 + sck * 8, &Ks[0][(wv * 256 + jj * 64) * 8]);
      int rowv = c2 >> 2, cv = c2 & 3, scv = cv ^ (rowv & 3);
      gload_lds16(Vbase + rowv * 32 + scv * 8, &Vs[0][(wv * 256 + jj * 64) * 8]);
    }
    __syncthreads();
    int cur = 0;
    for (int kt = 0; kt < 16; kt++) {
      if (kt < 15) {
        const __bf16* Kt = Kbase + (kt + 1) * 8192;
        const __bf16* Vt = Vbase + (kt + 1) * 8192;
#pragma unroll
        for (int jj = 0; jj < 4; jj++) {
          int c2 = ci + jj * 64;
          int rowk = c2 >> 3, ck = c2 & 7, sck = ck ^ (rowk & 7);
          gload_lds16(Kt + rowk * 64 + sck * 8, &Ks[cur ^ 1][(wv * 256 + jj * 64) * 8]);
          int rowv = c2 >> 2, cv = c2 & 3, scv = cv ^ (rowv & 3);
          gload_lds16(Vt + rowv * 32 + scv * 8, &Vs[cur ^ 1][(wv * 256 + jj * 64) * 8]);
        }
      }
      const __bf16* Kcur = Ks[cur];
      const char* Vcur = reinterpret_cast<const char*>(Vs[cur]);
#pragma unroll
      for (int w = 0; w < 4; w++) {              // windows of 32 k
        const __bf16* kr0 = &Kcur[(w * 32 + ln) * 64];
        const __bf16* kr1 = &Kcur[(w * 32 + 16 + ln) * 64];
        f32x4 d0 = (f32x4){0.f, 0.f, 0.f, 0.f}, d1 = (f32x4){0.f, 0.f, 0.f, 0.f};
        d0 = __builtin_amdgcn_mfma_f32_16x16x32_bf16(
            *reinterpret_cast<const bf16x8*>(kr0 + ((cg ^ sw7) * 8)), qf0, d0, 0, 0, 0);
        d0 = __builtin_amdgcn_mfma_f32_16x16x32_bf16(
            *reinterpret_cast<const bf16x8*>(kr0 + (((cg + 4) ^ sw7) * 8)), qf1, d0, 0, 0, 0);
        d1 = __builtin_amdgcn_mfma_f32_16x16x32_bf16(
            *reinterpret_cast<const bf16x8*>(kr1 + ((cg ^ sw7) * 8)), qf0, d1, 0, 0, 0);
        d1 = __builtin_amdgcn_mfma_f32_16x16x32_bf16(
            *reinterpret_cast<const bf16x8*>(kr1 + (((cg + 4) ^ sw7) * 8)), qf1, d1, 0, 0, 0);
        // p: d0 -> k = kt*128 + w*32 + cg*4 + r4 ; d1 -> +16
        float p0 = 1.f + __sinf(1.25f * (d0[0] - mu) * rs);
        float p1 = 1.f + __sinf(1.25f * (d0[1] - mu) * rs);
        float p2 = 1.f + __sinf(1.25f * (d0[2] - mu) * rs);
        float p3 = 1.f + __sinf(1.25f * (d0[3] - mu) * rs);
        float p4 = 1.f + __sinf(1.25f * (d1[0] - mu) * rs);
        float p5 = 1.f + __sinf(1.25f * (d1[1] - mu) * rs);
        float p6 = 1.f + __sinf(1.25f * (d1[2] - mu) * rs);
        float p7 = 1.f + __sinf(1.25f * (d1[3] - mu) * rs);
        f32x4 o0 = (f32x4){p0 * invZ, p1 * invZ, p2 * invZ, p3 * invZ};
        f32x4 o1 = (f32x4){p4 * invZ, p5 * invZ, p6 * invZ, p7 * invZ};
        *reinterpret_cast<f32x4*>(srow + kt * 128 + w * 32 + cg * 4) = o0;
        *reinterpret_cast<f32x4*>(srow + kt * 128 + w * 32 + 16 + cg * 4) = o1;
        // PV: B = P in slot order, A = V matching slots
        bf16x2 c0, c1, c2, c3;
        c0[0] = (__bf16)p0; c0[1] = (__bf16)p1;
        c1[0] = (__bf16)p2; c1[1] = (__bf16)p3;
        c2[0] = (__bf16)p4; c2[1] = (__bf16)p5;
        c3[0] = (__bf16)p6; c3[1] = (__bf16)p7;
        u32x4 pk = (u32x4){__builtin_bit_cast(unsigned, c0), __builtin_bit_cast(unsigned, c1),
                           __builtin_bit_cast(unsigned, c2), __builtin_bit_cast(unsigned, c3)};
        bf16x8 pf = __builtin_bit_cast(bf16x8, pk);
#pragma unroll
        for (int dt = 0; dt < 4; dt++) {
          const char* vr = Vcur + (w * 64 + dt * 16 + ln) * 64;
          int b0 = ((((cg >> 1) ^ sw3)) << 4) + ((cg & 1) << 3);
          int b1 = (((((cg >> 1) + 2) ^ sw3)) << 4) + ((cg & 1) << 3);
          u32x2 vlo = *reinterpret_cast<const u32x2*>(vr + b0);
          u32x2 vhi = *reinterpret_cast<const u32x2*>(vr + b1);
          u32x4 vpk = (u32x4){vlo[0], vlo[1], vhi[0], vhi[1]};
          bf16x8 vf = __builtin_bit_cast(bf16x8, vpk);
          hacc[dt] = __builtin_amdgcn_mfma_f32_16x16x32_bf16(vf, pf, hacc[dt], 0, 0, 0);
        }
      }
      __syncthreads();
      cur ^= 1;
    }
  }

  // ---- hv write ----
  {
    __bf16* hq = hv + ((long)(bb * 2048) + qrow) * 512 + hh * 64;
#pragma unroll
    for (int dt = 0; dt < 4; dt++) {
      bf16x2 w0, w1;
      w0[0] = (__bf16)(hacc[dt][0] * invZ);
      w0[1] = (__bf16)(hacc[dt][1] * invZ);
      w1[0] = (__bf16)(hacc[dt][2] * invZ);
      w1[1] = (__bf16)(hacc[dt][3] * invZ);
      *reinterpret_cast<bf16x2*>(hq + dt * 16 + cg * 4) = w0;
      *reinterpret_cast<bf16x2*>(hq + dt * 16 + cg * 4 + 2) = w1;
    }
  }
}

// ---------------- launch ----------------
extern "C" void kernel_launch(void* const* d_in, const int* in_sizes, int n_in,
                              void* d_out, int out_size, void* d_ws, size_t ws_size,
                              hipStream_t stream) {
  const float* x = (const float*)d_in[0];
  const float* norm_w = (const float*)d_in[1];
  const float* norm_b = (const float*)d_in[2];
  const float* qvk_w = (const float*)d_in[3];
  const float* qvk_b = (const float*)d_in[4];
  const float* concat_w = (const float*)d_in[5];
  const float* concat_b = (const float*)d_in[6];
  const float* mlp_norm_w = (const float*)d_in[7];
  const float* mlp_norm_b = (const float*)d_in[8];
  const float* mlp1_w = (const float*)d_in[9];
  const float* mlp1_b = (const float*)d_in[10];
  const float* mlp2_w = (const float*)d_in[11];
  const float* mlp2_b = (const float*)d_in[12];

  char* ws = (char*)d_ws;
  __bf16* qvk_wT = (__bf16*)(ws + 0);          // 1536x512
  __bf16* concat_wT = (__bf16*)(ws + 1572864); // 512x512
  __bf16* mlp1_wT = (__bf16*)(ws + 2097152);   // 1024x512
  __bf16* mlp2_wT = (__bf16*)(ws + 3145728);   // 512x1024
  __bf16* xn = (__bf16*)(ws + 4194304);        // 4096x512
  __bf16* Qh = (__bf16*)(ws + 8388608);        // (16 heads)x2048x64
  __bf16* Kh = (__bf16*)(ws + 12582912);       // (16 heads)x2048x64
  __bf16* Vp = (__bf16*)(ws + 16777216);       // (16 heads) 32-k panels
  __bf16* hv = (__bf16*)(ws + 20971520);       // 4096x512
  float* gpart = (float*)(ws + 25165824);      // 8MB (later reused as attout)
  float* attout = (float*)(ws + 25165824);     // 4096x512 fp32
  float* kpart = (float*)(ws + 33554432);      // 128KB
  float* G = (float*)(ws + 33685504);          // 256KB
  float* kbar = (float*)(ws + 33947648);       // 4KB
  float2* stats = (float2*)(ws + 33951744);    // 256KB
  __bf16* a_b = (__bf16*)(ws + 33554432);      // 4096x512 (after attn7)
  __bf16* h_b = (__bf16*)(ws + 37748736);      // 4096x1024

  float* out0 = (float*)d_out;
  float* sco = out0 + 2097152;  // scores (B,H,S,S) fp32

  wtrans_all<<<8192, 256, 0, stream>>>(qvk_w, concat_w, mlp1_w, mlp2_w,
                                       qvk_wT, concat_wT, mlp1_wT, mlp2_wT);

  ln_kernel<<<4096, 256, 0, stream>>>(x, norm_w, norm_b, xn);

  // qkv = relu(xn @ qvk_w + b); LDS-staged epilogue -> Qh/Kh/Vp
  gemm_kernel<1, 2, false><<<dim3(12, 32), 256, 0, stream>>>(
      xn, qvk_wT, qvk_b, nullptr, nullptr, Qh, Kh, Vp, 512, 512, 1536, 512);

  // per-head Gram + kbar -> per-row stats
  gram_kernel<<<512, 256, 0, stream>>>(Kh, gpart, kpart);
  greduce_kernel<<<260, 256, 0, stream>>>(gpart, kpart, G, kbar);
  stats_kernel<<<512, 256, 0, stream>>>(Qh, G, kbar, stats);

  // fused attention (scores -> out1, hv bf16), dbuf pipeline
  attn7_kernel<<<512, 256, 0, stream>>>(Qh, Kh, Vp, stats, sco, hv);

  // attout = hv @ concat_w + b + x (fp32)
  gemm_kernel<0, 0, true><<<dim3(4, 32), 256, 0, stream>>>(
      hv, concat_wT, concat_b, x, attout, nullptr, nullptr, nullptr, 512, 512, 512, 512);

  ln_kernel<<<4096, 256, 0, stream>>>(attout, mlp_norm_w, mlp_norm_b, a_b);

  // h = gelu(a @ mlp1_w + b)
  gemm_kernel<2, 1, false><<<dim3(8, 32), 256, 0, stream>>>(
      a_b, mlp1_wT, mlp1_b, nullptr, nullptr, h_b, nullptr, nullptr, 512, 512, 1024, 512);

  // out0 = h @ mlp2_w + b + attout
  gemm_kernel<0, 0, true><<<dim3(4, 32), 256, 0, stream>>>(
      h_b, mlp2_wT, mlp2_b, attout, out0, nullptr, nullptr, nullptr, 1024, 1024, 512, 1024);
}

// Round 13
// 199.518 us; speedup vs baseline: 1.1303x; 1.1303x over previous
//
#include <hip/hip_runtime.h>

// ---- problem constants ----
#define Bb_ 2
#define S_ 2048
#define D_ 512
#define H_ 8
#define DH_ 64

typedef __attribute__((ext_vector_type(8))) __bf16 bf16x8;
typedef __attribute__((ext_vector_type(4))) __bf16 bf16x4;
typedef __attribute__((ext_vector_type(2))) __bf16 bf16x2;
typedef __attribute__((ext_vector_type(4))) float f32x4;
typedef __attribute__((ext_vector_type(8))) short short8;
typedef __attribute__((ext_vector_type(4))) unsigned u32x4;
typedef __attribute__((ext_vector_type(2))) unsigned u32x2;

// direct global->LDS DMA, 16B per lane; dest = wave-uniform base + lane*16
__device__ __forceinline__ void gload_lds16(const void* g, void* l) {
  __builtin_amdgcn_global_load_lds(
      (const __attribute__((address_space(1))) unsigned int*)g,
      (__attribute__((address_space(3))) unsigned int*)l, 16, 0, 0);
}

// ---------------- LDS-tiled weight transpose + bf16 convert ----------------
// 64x64 tiles: coalesced fp32 reads (256B segments), LDS [n][k] (pad 72),
// coalesced bf16x8 row writes (full 128B chunks -> no partial-line RMW).
__global__ __launch_bounds__(256) void wtrans_tile(
    const float* __restrict__ qvk_w, const float* __restrict__ concat_w,
    const float* __restrict__ mlp1_w, const float* __restrict__ mlp2_w,
    __bf16* __restrict__ qvk_wT, __bf16* __restrict__ concat_wT,
    __bf16* __restrict__ mlp1_wT, __bf16* __restrict__ mlp2_wT) {
  __shared__ __align__(16) __bf16 tl[64 * 72];
  int b = blockIdx.x;
  const float* w;
  __bf16* wt;
  int K, N, rel, TN;
  if (b < 192)      { w = qvk_w;    wt = qvk_wT;    K = 512;  N = 1536; rel = b;       TN = 24; }
  else if (b < 256) { w = concat_w; wt = concat_wT; K = 512;  N = 512;  rel = b - 192; TN = 8;  }
  else if (b < 384) { w = mlp1_w;   wt = mlp1_wT;   K = 512;  N = 1024; rel = b - 256; TN = 16; }
  else              { w = mlp2_w;   wt = mlp2_wT;   K = 1024; N = 512;  rel = b - 384; TN = 8;  }
  int tk = rel / TN, tn = rel % TN;
  int k0 = tk * 64, n0 = tn * 64;
  int t = threadIdx.x;
#pragma unroll
  for (int i = 0; i < 4; i++) {
    int idx = i * 256 + t;
    int kk = idx >> 4, c4 = idx & 15;
    float4 v = *reinterpret_cast<const float4*>(w + (long)(k0 + kk) * N + n0 + c4 * 4);
    int nb = c4 * 4;
    tl[(nb + 0) * 72 + kk] = (__bf16)v.x;
    tl[(nb + 1) * 72 + kk] = (__bf16)v.y;
    tl[(nb + 2) * 72 + kk] = (__bf16)v.z;
    tl[(nb + 3) * 72 + kk] = (__bf16)v.w;
  }
  __syncthreads();
#pragma unroll
  for (int i = 0; i < 2; i++) {
    int idx = i * 256 + t;
    int nn = idx >> 3, kc = idx & 7;
    bf16x8 vv = *reinterpret_cast<const bf16x8*>(&tl[nn * 72 + kc * 8]);
    *reinterpret_cast<bf16x8*>(wt + (long)(n0 + nn) * K + k0 + kc * 8) = vv;
  }
}

// ---------------- layernorm (ddof=0), row length 512 ----------------
__global__ __launch_bounds__(256) void ln_kernel(const float* __restrict__ x,
                                                 const float* __restrict__ w,
                                                 const float* __restrict__ b,
                                                 __bf16* __restrict__ out) {
  long row = blockIdx.x;
  const float* xr = x + row * 512;
  int t = threadIdx.x;
  float2 v = *reinterpret_cast<const float2*>(xr + t * 2);
  float s = v.x + v.y;
  float sq = v.x * v.x + v.y * v.y;
#pragma unroll
  for (int m = 1; m < 64; m <<= 1) {
    s += __shfl_xor(s, m);
    sq += __shfl_xor(sq, m);
  }
  __shared__ float red[8];
  int wid = t >> 6;
  if ((t & 63) == 0) { red[wid] = s; red[wid + 4] = sq; }
  __syncthreads();
  s = red[0] + red[1] + red[2] + red[3];
  sq = red[4] + red[5] + red[6] + red[7];
  float mu = s * (1.f / 512.f);
  float var = sq * (1.f / 512.f) - mu * mu;
  float rs = rsqrtf(var + 1e-5f);
  int c = t * 2;
  float o0 = (v.x - mu) * rs * w[c] + b[c];
  float o1 = (v.y - mu) * rs * w[c + 1] + b[c + 1];
  bf16x2 ov;
  ov[0] = (__bf16)o0;
  ov[1] = (__bf16)o1;
  *reinterpret_cast<bf16x2*>(out + row * 512 + c) = ov;
}

// ---------------- generic bf16 MFMA GEMM (global_load_lds staging) ----------
// BM = 128: 4 waves 2x2 (wave 64x64), OUTMODE 0/1/2.
// BM = 64:  4 waves 1x4 (wave 64x32), OUTMODE 0/1 — doubles grid for skinny N.
template <int ACT, int OUTMODE, bool HASRES, int BM>
__global__ __launch_bounds__(256) void gemm_kernel(
    const __bf16* __restrict__ A, const __bf16* __restrict__ Bt,
    const float* __restrict__ bias, const float* __restrict__ res,
    float* __restrict__ outF, __bf16* __restrict__ outB,
    __bf16* __restrict__ outK, __bf16* __restrict__ outVt,
    int lda, int ldb, int ldc, int K) {
  __shared__ __align__(16) __bf16 smem[BM * 64 + 128 * 64];
  __bf16* As = smem;
  __bf16* Bs = smem + BM * 64;
  int t = threadIdx.x, lane = t & 63, wid = t >> 6;
  const __bf16* Ab = A + (long)blockIdx.y * BM * lda;
  const __bf16* Bb = Bt + (long)blockIdx.x * 128 * ldb;

  constexpr int WM = (BM == 128) ? 2 : 1;   // waves along M
  constexpr int FN = (BM == 128) ? 4 : 2;   // wave N-frags (N-extent 16*FN)
  int wr = (WM == 2) ? (wid >> 1) : 0;
  int wc = (WM == 2) ? (wid & 1) : wid;
  int kq = lane >> 4;

  f32x4 acc[4][FN];
#pragma unroll
  for (int i = 0; i < 4; i++)
#pragma unroll
    for (int j = 0; j < FN; j++) acc[i][j] = (f32x4){0.f, 0.f, 0.f, 0.f};

  for (int k0 = 0; k0 < K; k0 += 64) {
    __syncthreads();
    // A tile: BM*8 chunks of 16B
#pragma unroll
    for (int j = 0; j < BM / 32; j++) {
      int ci = wid * (BM * 2) + j * 64 + lane;
      int row = ci >> 3, c = ci & 7, sc = c ^ (row & 7);
      gload_lds16(Ab + (long)row * lda + k0 + sc * 8, &As[(wid * (BM * 2) + j * 64) * 8]);
    }
    // B tile: 1024 chunks
#pragma unroll
    for (int j = 0; j < 4; j++) {
      int ci = wid * 256 + j * 64 + lane;
      int row = ci >> 3, c = ci & 7, sc = c ^ (row & 7);
      gload_lds16(Bb + (long)row * ldb + k0 + sc * 8, &Bs[(wid * 256 + j * 64) * 8]);
    }
    __syncthreads();
#pragma unroll
    for (int ks = 0; ks < 2; ks++) {
      bf16x8 af[4], bfr[FN];
#pragma unroll
      for (int fm = 0; fm < 4; fm++) {
        int r = wr * 64 + fm * 16 + (lane & 15);
        int c = (ks * 4 + kq) ^ (r & 7);
        af[fm] = *reinterpret_cast<const bf16x8*>(&As[r * 64 + c * 8]);
      }
#pragma unroll
      for (int fn = 0; fn < FN; fn++) {
        int r = wc * (16 * FN) + fn * 16 + (lane & 15);
        int c = (ks * 4 + kq) ^ (r & 7);
        bfr[fn] = *reinterpret_cast<const bf16x8*>(&Bs[r * 64 + c * 8]);
      }
#pragma unroll
      for (int fm = 0; fm < 4; fm++)
#pragma unroll
        for (int fn = 0; fn < FN; fn++)
          acc[fm][fn] = __builtin_amdgcn_mfma_f32_16x16x32_bf16(af[fm], bfr[fn],
                                                                acc[fm][fn], 0, 0, 0);
    }
  }

  if constexpr (OUTMODE == 2) {
    // qkv scatter epilogue (BM==128 only): acc -> Cs -> coalesced Qh/Kh/Vp
    __syncthreads();
    char* Cb = reinterpret_cast<char*>(smem);
#pragma unroll
    for (int fm = 0; fm < 4; fm++)
#pragma unroll
      for (int fn = 0; fn < FN; fn++) {
        int c = wc * 64 + fn * 16 + (lane & 15);
        int gcol = blockIdx.x * 128 + c;
        float bv = bias[gcol];
#pragma unroll
        for (int r4 = 0; r4 < 4; r4++) {
          int r = wr * 64 + fm * 16 + kq * 4 + r4;
          float v = fmaxf(acc[fm][fn][r4] + bv, 0.f);  // relu
          *reinterpret_cast<__bf16*>(Cb + r * 256 + (((c >> 3) ^ (r & 7)) << 4) +
                                     ((c & 7) << 1)) = (__bf16)v;
        }
      }
    __syncthreads();
    long bbq = (blockIdx.y * 128) >> 11;
    int srow0 = (blockIdx.y * 128) & 2047;
    if (blockIdx.x < 8) {
      int r = t >> 1, half = t & 1;
      int gcol = blockIdx.x * 128 + half * 64;
      __bf16* dst;
      if (gcol < 512)
        dst = outB + ((bbq * 8 + (gcol >> 6)) * 2048 + srow0 + r) * 64;
      else
        dst = outK + ((bbq * 8 + ((gcol - 512) >> 6)) * 2048 + srow0 + r) * 64;
      const char* srcrow = Cb + r * 256;
#pragma unroll
      for (int j = 0; j < 8; j++) {
        bf16x8 vv = *reinterpret_cast<const bf16x8*>(
            srcrow + ((((half * 8 + j) ^ (r & 7))) << 4));
        *reinterpret_cast<bf16x8*>(dst + j * 8) = vv;
      }
    } else {
      int d = t & 63, seg = t >> 6;
      int srow = srow0 + seg * 32;
#pragma unroll
      for (int h2 = 0; h2 < 2; h2++) {
        int c = h2 * 64 + d;
        int h = (blockIdx.x * 128 - 1024 + h2 * 64) >> 6;
        __bf16* dst = outVt + (bbq * 8 + h) * 131072 + (srow >> 5) * 2048 + d * 32;
        bf16x8 wv8[4];
#pragma unroll
        for (int i = 0; i < 32; i++) {
          int r = seg * 32 + i;
          __bf16 val = *reinterpret_cast<const __bf16*>(
              Cb + r * 256 + (((c >> 3) ^ (r & 7)) << 4) + ((c & 7) << 1));
          wv8[i >> 3][i & 7] = val;
        }
#pragma unroll
        for (int i4 = 0; i4 < 4; i4++)
          *reinterpret_cast<bf16x8*>(dst + i4 * 8) = wv8[i4];
      }
    }
    return;
  } else {
    long gr0 = (long)blockIdx.y * BM + wr * 64;
    long gc0 = (long)blockIdx.x * 128 + wc * (16 * FN);
#pragma unroll
    for (int fm = 0; fm < 4; fm++)
#pragma unroll
      for (int fn = 0; fn < FN; fn++) {
        int col = (int)gc0 + fn * 16 + (lane & 15);
        long rbase = gr0 + fm * 16 + kq * 4;
        float bv = bias ? bias[col] : 0.f;
#pragma unroll
        for (int r4 = 0; r4 < 4; r4++) {
          long grow = rbase + r4;
          float v = acc[fm][fn][r4] + bv;
          if (HASRES) v += res[grow * ldc + col];
          if (ACT == 1) v = fmaxf(v, 0.f);
          if (ACT == 2) v = 0.5f * v * (1.f + erff(v * 0.70710678118f));
          if (OUTMODE == 0) {
            outF[grow * ldc + col] = v;
          } else {
            outB[grow * ldc + col] = (__bf16)v;
          }
        }
      }
  }
}

// ---------------- Gram partials: per (head, 64-k chunk) G-part + kbar-part ----
__global__ __launch_bounds__(256) void gram_kernel(const __bf16* __restrict__ Kh,
                                                   float* __restrict__ gpart,
                                                   float* __restrict__ kpart) {
  int head = blockIdx.x >> 5, chunk = blockIdx.x & 31;
  __shared__ __align__(16) __bf16 kl[64 * 64];
  int t = threadIdx.x;
  const __bf16* src = Kh + ((long)head * 2048 + chunk * 64) * 64;
#pragma unroll
  for (int i = 0; i < 2; i++) {
    int e = (i * 256 + t) * 8;
    *reinterpret_cast<short8*>(&kl[e]) = *reinterpret_cast<const short8*>(&src[e]);
  }
  __syncthreads();
  int d1 = t & 63, g = t >> 6;
  float acc[16];
#pragma unroll
  for (int i = 0; i < 16; i++) acc[i] = 0.f;
  float kb = 0.f;
  for (int r = 0; r < 64; r++) {
    float k1 = (float)kl[r * 64 + d1];
    kb += k1;
    bf16x8 a = *reinterpret_cast<const bf16x8*>(&kl[r * 64 + g * 16]);
    bf16x8 b = *reinterpret_cast<const bf16x8*>(&kl[r * 64 + g * 16 + 8]);
#pragma unroll
    for (int i = 0; i < 8; i++) acc[i] += k1 * (float)a[i];
#pragma unroll
    for (int i = 0; i < 8; i++) acc[8 + i] += k1 * (float)b[i];
  }
  float* gp = gpart + ((long)chunk * 16 + head) * 4096 + d1 * 64 + g * 16;
#pragma unroll
  for (int i = 0; i < 16; i++) gp[i] = acc[i];
  if (g == 0) kpart[(chunk * 16 + head) * 64 + d1] = kb;
}

// ---------------- reduce Gram partials -> G (fp32), kbar ----------------
__global__ __launch_bounds__(256) void greduce_kernel(const float* __restrict__ gpart,
                                                      const float* __restrict__ kpart,
                                                      float* __restrict__ G,
                                                      float* __restrict__ kbar) {
  int idx = blockIdx.x * 256 + threadIdx.x;
  if (idx < 65536) {
    int head = idx >> 12, e = idx & 4095;
    float s = 0.f;
#pragma unroll 4
    for (int c = 0; c < 32; c++) s += gpart[((long)c * 16 + head) * 4096 + e];
    G[idx] = s;
  } else if (idx < 66560) {
    int k = idx - 65536;
    int head = k >> 6, d = k & 63;
    float s = 0.f;
#pragma unroll 4
    for (int c = 0; c < 32; c++) s += kpart[(c * 16 + head) * 64 + d];
    kbar[k] = s * (1.f / 2048.f);
  }
}

// ---------------- per-row stats: mu = q.kbar ; s2 = q^T G q -> (mu, rsqrt) ----
__global__ __launch_bounds__(256, 4) void stats_kernel(const __bf16* __restrict__ Qh,
                                                       const float* __restrict__ G,
                                                       const float* __restrict__ kbar,
                                                       float2* __restrict__ stats) {
  int head = blockIdx.x >> 5, sub = blockIdx.x & 31;
  __shared__ float Gl[4096];
  __shared__ float kbl[64];
  __shared__ __align__(16) float qlf[64 * 68];
  int t = threadIdx.x;
  const float* Gsrc = G + head * 4096;
#pragma unroll
  for (int i = 0; i < 4; i++) {
    int e = (i * 256 + t) * 4;
    *reinterpret_cast<float4*>(&Gl[e]) = *reinterpret_cast<const float4*>(&Gsrc[e]);
  }
  if (t < 16)
    *reinterpret_cast<float4*>(&kbl[t * 4]) =
        *reinterpret_cast<const float4*>(&kbar[head * 64 + t * 4]);
  const __bf16* qsrc = Qh + ((long)head * 2048 + sub * 64) * 64;
#pragma unroll
  for (int i = 0; i < 2; i++) {
    int e = (i * 256 + t) * 8;
    bf16x8 v = *reinterpret_cast<const bf16x8*>(&qsrc[e]);
    int row = e >> 6, col = e & 63;
    float* dst = &qlf[row * 68 + col];
#pragma unroll
    for (int j = 0; j < 8; j++) dst[j] = (float)v[j];
  }
  __syncthreads();
  int qrow = t >> 2, qt = t & 3;
  const float* qr = &qlf[qrow * 68];
  float mup = 0.f, s2p = 0.f;
#pragma unroll
  for (int i = 0; i < 16; i++) {
    int d1 = qt * 16 + i;
    const float* Gr = &Gl[d1 * 64];
    float acc = 0.f;
#pragma unroll
    for (int j = 0; j < 64; j++) acc += Gr[j] * qr[j];
    float q1 = qr[d1];
    s2p += q1 * acc;
    mup += q1 * kbl[d1];
  }
  mup += __shfl_xor(mup, 1); mup += __shfl_xor(mup, 2);
  s2p += __shfl_xor(s2p, 1); s2p += __shfl_xor(s2p, 2);
  if (qt == 0) {
    float mu = mup;
    float var = (s2p - 2048.f * mu * mu) * (1.f / 2047.f);
    stats[(head << 11) + sub * 64 + qrow] = make_float2(mu, rsqrtf(var + 1e-5f));
  }
}

// ---------------- attn6: GEMM-shaped fused attention (single-buffer) --------
__global__ __launch_bounds__(256) void attn6_kernel(
    const __bf16* __restrict__ Qh, const __bf16* __restrict__ Kh,
    const __bf16* __restrict__ Vp, const float2* __restrict__ stats,
    float* __restrict__ sco, __bf16* __restrict__ hv) {
  __shared__ __align__(16) __bf16 Ks[128 * 64];       // 16 KB, chunk c at c^(row&7)
  __shared__ __align__(16) __bf16 Vs[4 * 64 * 32];    // 16 KB, chunk c at c^(row&3)

  int bid = blockIdx.x;                  // 512 blocks
  int xcd = bid & 7, j = bid >> 3;
  int head = xcd * 2 + (j >> 5);
  int qt = j & 31;
  int bb = head >> 3, hh = head & 7;
  int q0 = qt * 64;

  int t = threadIdx.x, lane = t & 63, wv = t >> 6;  // 4 waves
  int cg = lane >> 4, ln = lane & 15;
  int sw7 = ln & 7, sw3 = ln & 3;

  int qrow = q0 + wv * 16 + ln;
  const __bf16* Qr = Qh + ((long)head * 2048 + qrow) * 64;
  bf16x8 qf0 = *reinterpret_cast<const bf16x8*>(Qr + cg * 8);
  bf16x8 qf1 = *reinterpret_cast<const bf16x8*>(Qr + 32 + cg * 8);
  float2 st = stats[(head << 11) + qrow];
  float mu = st.x, rs = st.y;

  const __bf16* Kbase = Kh + (long)head * 131072;
  const __bf16* Vbase = Vp + (long)head * 131072;

  // ---- pass 1: Z only ----
  float Z = 0.f;
  for (int kt = 0; kt < 16; kt++) {
    __syncthreads();
    const __bf16* Kt = Kbase + kt * 8192;
#pragma unroll
    for (int jj = 0; jj < 4; jj++) {
      int ci = wv * 256 + jj * 64 + lane;
      int row = ci >> 3, c = ci & 7, sc = c ^ (row & 7);
      gload_lds16(Kt + row * 64 + sc * 8, &Ks[(wv * 256 + jj * 64) * 8]);
    }
    __syncthreads();
#pragma unroll
    for (int sl = 0; sl < 8; sl++) {
      const __bf16* kr = &Ks[(sl * 16 + ln) * 64];
      bf16x8 a0 = *reinterpret_cast<const bf16x8*>(kr + ((cg ^ sw7) * 8));
      bf16x8 a1 = *reinterpret_cast<const bf16x8*>(kr + (((cg + 4) ^ sw7) * 8));
      f32x4 d = (f32x4){0.f, 0.f, 0.f, 0.f};
      d = __builtin_amdgcn_mfma_f32_16x16x32_bf16(a0, qf0, d, 0, 0, 0);
      d = __builtin_amdgcn_mfma_f32_16x16x32_bf16(a1, qf1, d, 0, 0, 0);
      Z += (1.f + __sinf(1.25f * (d[0] - mu) * rs));
      Z += (1.f + __sinf(1.25f * (d[1] - mu) * rs));
      Z += (1.f + __sinf(1.25f * (d[2] - mu) * rs));
      Z += (1.f + __sinf(1.25f * (d[3] - mu) * rs));
    }
  }
  Z += __shfl_xor(Z, 16);
  Z += __shfl_xor(Z, 32);
  float invZ = 1.f / Z;

  // ---- pass 2: scores + PV ----
  f32x4 hacc[4];
#pragma unroll
  for (int dt = 0; dt < 4; dt++) hacc[dt] = (f32x4){0.f, 0.f, 0.f, 0.f};
  float* srow = sco + ((long)head * 2048 + qrow) * 2048;

  for (int kt = 0; kt < 16; kt++) {
    __syncthreads();
    const __bf16* Kt = Kbase + kt * 8192;
    const __bf16* Vt = Vbase + kt * 8192;
#pragma unroll
    for (int jj = 0; jj < 4; jj++) {
      int ci = wv * 256 + jj * 64 + lane;
      int rowk = ci >> 3, ck = ci & 7, sck = ck ^ (rowk & 7);
      gload_lds16(Kt + rowk * 64 + sck * 8, &Ks[(wv * 256 + jj * 64) * 8]);
      int rowv = ci >> 2, cv = ci & 3, scv = cv ^ (rowv & 3);
      gload_lds16(Vt + rowv * 32 + scv * 8, &Vs[(wv * 256 + jj * 64) * 8]);
    }
    __syncthreads();
#pragma unroll
    for (int w = 0; w < 4; w++) {
      const __bf16* kr0 = &Ks[(w * 32 + ln) * 64];
      const __bf16* kr1 = &Ks[(w * 32 + 16 + ln) * 64];
      f32x4 d0 = (f32x4){0.f, 0.f, 0.f, 0.f}, d1 = (f32x4){0.f, 0.f, 0.f, 0.f};
      d0 = __builtin_amdgcn_mfma_f32_16x16x32_bf16(
          *reinterpret_cast<const bf16x8*>(kr0 + ((cg ^ sw7) * 8)), qf0, d0, 0, 0, 0);
      d0 = __builtin_amdgcn_mfma_f32_16x16x32_bf16(
          *reinterpret_cast<const bf16x8*>(kr0 + (((cg + 4) ^ sw7) * 8)), qf1, d0, 0, 0, 0);
      d1 = __builtin_amdgcn_mfma_f32_16x16x32_bf16(
          *reinterpret_cast<const bf16x8*>(kr1 + ((cg ^ sw7) * 8)), qf0, d1, 0, 0, 0);
      d1 = __builtin_amdgcn_mfma_f32_16x16x32_bf16(
          *reinterpret_cast<const bf16x8*>(kr1 + (((cg + 4) ^ sw7) * 8)), qf1, d1, 0, 0, 0);
      float p0 = 1.f + __sinf(1.25f * (d0[0] - mu) * rs);
      float p1 = 1.f + __sinf(1.25f * (d0[1] - mu) * rs);
      float p2 = 1.f + __sinf(1.25f * (d0[2] - mu) * rs);
      float p3 = 1.f + __sinf(1.25f * (d0[3] - mu) * rs);
      float p4 = 1.f + __sinf(1.25f * (d1[0] - mu) * rs);
      float p5 = 1.f + __sinf(1.25f * (d1[1] - mu) * rs);
      float p6 = 1.f + __sinf(1.25f * (d1[2] - mu) * rs);
      float p7 = 1.f + __sinf(1.25f * (d1[3] - mu) * rs);
      f32x4 o0 = (f32x4){p0 * invZ, p1 * invZ, p2 * invZ, p3 * invZ};
      f32x4 o1 = (f32x4){p4 * invZ, p5 * invZ, p6 * invZ, p7 * invZ};
      *reinterpret_cast<f32x4*>(srow + kt * 128 + w * 32 + cg * 4) = o0;
      *reinterpret_cast<f32x4*>(srow + kt * 128 + w * 32 + 16 + cg * 4) = o1;
      bf16x2 c0, c1, c2, c3;
      c0[0] = (__bf16)p0; c0[1] = (__bf16)p1;
      c1[0] = (__bf16)p2; c1[1] = (__bf16)p3;
      c2[0] = (__bf16)p4; c2[1] = (__bf16)p5;
      c3[0] = (__bf16)p6; c3[1] = (__bf16)p7;
      u32x4 pk = (u32x4){__builtin_bit_cast(unsigned, c0), __builtin_bit_cast(unsigned, c1),
                         __builtin_bit_cast(unsigned, c2), __builtin_bit_cast(unsigned, c3)};
      bf16x8 pf = __builtin_bit_cast(bf16x8, pk);
#pragma unroll
      for (int dt = 0; dt < 4; dt++) {
        const char* vr = reinterpret_cast<const char*>(Vs) + (w * 64 + dt * 16 + ln) * 64;
        int b0 = ((((cg >> 1) ^ sw3)) << 4) + ((cg & 1) << 3);
        int b1 = (((((cg >> 1) + 2) ^ sw3)) << 4) + ((cg & 1) << 3);
        u32x2 vlo = *reinterpret_cast<const u32x2*>(vr + b0);
        u32x2 vhi = *reinterpret_cast<const u32x2*>(vr + b1);
        u32x4 vpk = (u32x4){vlo[0], vlo[1], vhi[0], vhi[1]};
        bf16x8 vf = __builtin_bit_cast(bf16x8, vpk);
        hacc[dt] = __builtin_amdgcn_mfma_f32_16x16x32_bf16(vf, pf, hacc[dt], 0, 0, 0);
      }
    }
  }

  // ---- hv write ----
  {
    __bf16* hq = hv + ((long)(bb * 2048) + qrow) * 512 + hh * 64;
#pragma unroll
    for (int dt = 0; dt < 4; dt++) {
      bf16x2 w0, w1;
      w0[0] = (__bf16)(hacc[dt][0] * invZ);
      w0[1] = (__bf16)(hacc[dt][1] * invZ);
      w1[0] = (__bf16)(hacc[dt][2] * invZ);
      w1[1] = (__bf16)(hacc[dt][3] * invZ);
      *reinterpret_cast<bf16x2*>(hq + dt * 16 + cg * 4) = w0;
      *reinterpret_cast<bf16x2*>(hq + dt * 16 + cg * 4 + 2) = w1;
    }
  }
}

// ---------------- launch ----------------
extern "C" void kernel_launch(void* const* d_in, const int* in_sizes, int n_in,
                              void* d_out, int out_size, void* d_ws, size_t ws_size,
                              hipStream_t stream) {
  const float* x = (const float*)d_in[0];
  const float* norm_w = (const float*)d_in[1];
  const float* norm_b = (const float*)d_in[2];
  const float* qvk_w = (const float*)d_in[3];
  const float* qvk_b = (const float*)d_in[4];
  const float* concat_w = (const float*)d_in[5];
  const float* concat_b = (const float*)d_in[6];
  const float* mlp_norm_w = (const float*)d_in[7];
  const float* mlp_norm_b = (const float*)d_in[8];
  const float* mlp1_w = (const float*)d_in[9];
  const float* mlp1_b = (const float*)d_in[10];
  const float* mlp2_w = (const float*)d_in[11];
  const float* mlp2_b = (const float*)d_in[12];

  char* ws = (char*)d_ws;
  __bf16* qvk_wT = (__bf16*)(ws + 0);          // 1536x512
  __bf16* concat_wT = (__bf16*)(ws + 1572864); // 512x512
  __bf16* mlp1_wT = (__bf16*)(ws + 2097152);   // 1024x512
  __bf16* mlp2_wT = (__bf16*)(ws + 3145728);   // 512x1024
  __bf16* xn = (__bf16*)(ws + 4194304);        // 4096x512
  __bf16* Qh = (__bf16*)(ws + 8388608);        // (16 heads)x2048x64
  __bf16* Kh = (__bf16*)(ws + 12582912);       // (16 heads)x2048x64
  __bf16* Vp = (__bf16*)(ws + 16777216);       // (16 heads) 32-k panels
  __bf16* hv = (__bf16*)(ws + 20971520);       // 4096x512
  float* gpart = (float*)(ws + 25165824);      // 8MB (later reused as attout)
  float* attout = (float*)(ws + 25165824);     // 4096x512 fp32
  float* kpart = (float*)(ws + 33554432);      // 128KB
  float* G = (float*)(ws + 33685504);          // 256KB
  float* kbar = (float*)(ws + 33947648);       // 4KB
  float2* stats = (float2*)(ws + 33951744);    // 256KB
  __bf16* a_b = (__bf16*)(ws + 33554432);      // 4096x512 (after attn6)
  __bf16* h_b = (__bf16*)(ws + 37748736);      // 4096x1024

  float* out0 = (float*)d_out;
  float* sco = out0 + 2097152;  // scores (B,H,S,S) fp32

  wtrans_tile<<<512, 256, 0, stream>>>(qvk_w, concat_w, mlp1_w, mlp2_w,
                                       qvk_wT, concat_wT, mlp1_wT, mlp2_wT);

  ln_kernel<<<4096, 256, 0, stream>>>(x, norm_w, norm_b, xn);

  // qkv = relu(xn @ qvk_w + b); LDS-staged epilogue -> Qh/Kh/Vp
  gemm_kernel<1, 2, false, 128><<<dim3(12, 32), 256, 0, stream>>>(
      xn, qvk_wT, qvk_b, nullptr, nullptr, Qh, Kh, Vp, 512, 512, 1536, 512);

  // per-head Gram + kbar -> per-row stats
  gram_kernel<<<512, 256, 0, stream>>>(Kh, gpart, kpart);
  greduce_kernel<<<260, 256, 0, stream>>>(gpart, kpart, G, kbar);
  stats_kernel<<<512, 256, 0, stream>>>(Qh, G, kbar, stats);

  // fused attention (scores -> out1, hv bf16)
  attn6_kernel<<<512, 256, 0, stream>>>(Qh, Kh, Vp, stats, sco, hv);

  // attout = hv @ concat_w + b + x (fp32); BM=64 -> 256 blocks
  gemm_kernel<0, 0, true, 64><<<dim3(4, 64), 256, 0, stream>>>(
      hv, concat_wT, concat_b, x, attout, nullptr, nullptr, nullptr, 512, 512, 512, 512);

  ln_kernel<<<4096, 256, 0, stream>>>(attout, mlp_norm_w, mlp_norm_b, a_b);

  // h = gelu(a @ mlp1_w + b); BM=64 -> 512 blocks
  gemm_kernel<2, 1, false, 64><<<dim3(8, 64), 256, 0, stream>>>(
      a_b, mlp1_wT, mlp1_b, nullptr, nullptr, h_b, nullptr, nullptr, 512, 512, 1024, 512);

  // out0 = h @ mlp2_w + b + attout; BM=64 -> 256 blocks
  gemm_kernel<0, 0, true, 64><<<dim3(4, 64), 256, 0, stream>>>(
      h_b, mlp2_wT, mlp2_b, attout, out0, nullptr, nullptr, nullptr, 1024, 1024, 512, 1024);
}

// Round 14
// 194.316 us; speedup vs baseline: 1.1606x; 1.0268x over previous
//
#include <hip/hip_runtime.h>

// ---- problem constants ----
#define Bb_ 2
#define S_ 2048
#define D_ 512
#define H_ 8
#define DH_ 64

typedef __attribute__((ext_vector_type(8))) __bf16 bf16x8;
typedef __attribute__((ext_vector_type(4))) __bf16 bf16x4;
typedef __attribute__((ext_vector_type(2))) __bf16 bf16x2;
typedef __attribute__((ext_vector_type(4))) float f32x4;
typedef __attribute__((ext_vector_type(8))) short short8;
typedef __attribute__((ext_vector_type(4))) unsigned u32x4;
typedef __attribute__((ext_vector_type(2))) unsigned u32x2;

// direct global->LDS DMA, 16B per lane; dest = wave-uniform base + lane*16
__device__ __forceinline__ void gload_lds16(const void* g, void* l) {
  __builtin_amdgcn_global_load_lds(
      (const __attribute__((address_space(1))) unsigned int*)g,
      (__attribute__((address_space(3))) unsigned int*)l, 16, 0, 0);
}

// ---------------- prep: weight transpose tiles (blocks 0-511) + LN (512+) ----
__global__ __launch_bounds__(256) void prep_kernel(
    const float* __restrict__ qvk_w, const float* __restrict__ concat_w,
    const float* __restrict__ mlp1_w, const float* __restrict__ mlp2_w,
    __bf16* __restrict__ qvk_wT, __bf16* __restrict__ concat_wT,
    __bf16* __restrict__ mlp1_wT, __bf16* __restrict__ mlp2_wT,
    const float* __restrict__ x, const float* __restrict__ norm_w,
    const float* __restrict__ norm_b, __bf16* __restrict__ xn) {
  int b = blockIdx.x;
  int t = threadIdx.x;
  if (b < 512) {
    // 64x64 transpose tile: coalesced fp32 reads, LDS [n][k] pad 72, bf16x8 writes
    __shared__ __align__(16) __bf16 tl[64 * 72];
    const float* w;
    __bf16* wt;
    int K, N, rel, TN;
    if (b < 192)      { w = qvk_w;    wt = qvk_wT;    K = 512;  N = 1536; rel = b;       TN = 24; }
    else if (b < 256) { w = concat_w; wt = concat_wT; K = 512;  N = 512;  rel = b - 192; TN = 8;  }
    else if (b < 384) { w = mlp1_w;   wt = mlp1_wT;   K = 512;  N = 1024; rel = b - 256; TN = 16; }
    else              { w = mlp2_w;   wt = mlp2_wT;   K = 1024; N = 512;  rel = b - 384; TN = 8;  }
    int tk = rel / TN, tn = rel % TN;
    int k0 = tk * 64, n0 = tn * 64;
#pragma unroll
    for (int i = 0; i < 4; i++) {
      int idx = i * 256 + t;
      int kk = idx >> 4, c4 = idx & 15;
      float4 v = *reinterpret_cast<const float4*>(w + (long)(k0 + kk) * N + n0 + c4 * 4);
      int nb = c4 * 4;
      tl[(nb + 0) * 72 + kk] = (__bf16)v.x;
      tl[(nb + 1) * 72 + kk] = (__bf16)v.y;
      tl[(nb + 2) * 72 + kk] = (__bf16)v.z;
      tl[(nb + 3) * 72 + kk] = (__bf16)v.w;
    }
    __syncthreads();
#pragma unroll
    for (int i = 0; i < 2; i++) {
      int idx = i * 256 + t;
      int nn = idx >> 3, kc = idx & 7;
      bf16x8 vv = *reinterpret_cast<const bf16x8*>(&tl[nn * 72 + kc * 8]);
      *reinterpret_cast<bf16x8*>(wt + (long)(n0 + nn) * K + k0 + kc * 8) = vv;
    }
  } else {
    // layernorm row
    long row = b - 512;
    const float* xr = x + row * 512;
    float2 v = *reinterpret_cast<const float2*>(xr + t * 2);
    float s = v.x + v.y;
    float sq = v.x * v.x + v.y * v.y;
#pragma unroll
    for (int m = 1; m < 64; m <<= 1) {
      s += __shfl_xor(s, m);
      sq += __shfl_xor(sq, m);
    }
    __shared__ float red[8];
    int wid = t >> 6;
    if ((t & 63) == 0) { red[wid] = s; red[wid + 4] = sq; }
    __syncthreads();
    s = red[0] + red[1] + red[2] + red[3];
    sq = red[4] + red[5] + red[6] + red[7];
    float mu = s * (1.f / 512.f);
    float var = sq * (1.f / 512.f) - mu * mu;
    float rs = rsqrtf(var + 1e-5f);
    int c = t * 2;
    float o0 = (v.x - mu) * rs * norm_w[c] + norm_b[c];
    float o1 = (v.y - mu) * rs * norm_w[c + 1] + norm_b[c + 1];
    bf16x2 ov;
    ov[0] = (__bf16)o0;
    ov[1] = (__bf16)o1;
    *reinterpret_cast<bf16x2*>(xn + row * 512 + c) = ov;
  }
}

// ---------------- layernorm (ddof=0), row length 512 ----------------
__global__ __launch_bounds__(256) void ln_kernel(const float* __restrict__ x,
                                                 const float* __restrict__ w,
                                                 const float* __restrict__ b,
                                                 __bf16* __restrict__ out) {
  long row = blockIdx.x;
  const float* xr = x + row * 512;
  int t = threadIdx.x;
  float2 v = *reinterpret_cast<const float2*>(xr + t * 2);
  float s = v.x + v.y;
  float sq = v.x * v.x + v.y * v.y;
#pragma unroll
  for (int m = 1; m < 64; m <<= 1) {
    s += __shfl_xor(s, m);
    sq += __shfl_xor(sq, m);
  }
  __shared__ float red[8];
  int wid = t >> 6;
  if ((t & 63) == 0) { red[wid] = s; red[wid + 4] = sq; }
  __syncthreads();
  s = red[0] + red[1] + red[2] + red[3];
  sq = red[4] + red[5] + red[6] + red[7];
  float mu = s * (1.f / 512.f);
  float var = sq * (1.f / 512.f) - mu * mu;
  float rs = rsqrtf(var + 1e-5f);
  int c = t * 2;
  float o0 = (v.x - mu) * rs * w[c] + b[c];
  float o1 = (v.y - mu) * rs * w[c + 1] + b[c + 1];
  bf16x2 ov;
  ov[0] = (__bf16)o0;
  ov[1] = (__bf16)o1;
  *reinterpret_cast<bf16x2*>(out + row * 512 + c) = ov;
}

// ---------------- generic bf16 MFMA GEMM (global_load_lds staging) ----------
template <int ACT, int OUTMODE, bool HASRES, int BM>
__global__ __launch_bounds__(256) void gemm_kernel(
    const __bf16* __restrict__ A, const __bf16* __restrict__ Bt,
    const float* __restrict__ bias, const float* __restrict__ res,
    float* __restrict__ outF, __bf16* __restrict__ outB,
    __bf16* __restrict__ outK, __bf16* __restrict__ outVt,
    int lda, int ldb, int ldc, int K) {
  __shared__ __align__(16) __bf16 smem[BM * 64 + 128 * 64];
  __bf16* As = smem;
  __bf16* Bs = smem + BM * 64;
  int t = threadIdx.x, lane = t & 63, wid = t >> 6;
  const __bf16* Ab = A + (long)blockIdx.y * BM * lda;
  const __bf16* Bb = Bt + (long)blockIdx.x * 128 * ldb;

  constexpr int WM = (BM == 128) ? 2 : 1;
  constexpr int FN = (BM == 128) ? 4 : 2;
  int wr = (WM == 2) ? (wid >> 1) : 0;
  int wc = (WM == 2) ? (wid & 1) : wid;
  int kq = lane >> 4;

  f32x4 acc[4][FN];
#pragma unroll
  for (int i = 0; i < 4; i++)
#pragma unroll
    for (int j = 0; j < FN; j++) acc[i][j] = (f32x4){0.f, 0.f, 0.f, 0.f};

  for (int k0 = 0; k0 < K; k0 += 64) {
    __syncthreads();
#pragma unroll
    for (int j = 0; j < BM / 32; j++) {
      int ci = wid * (BM * 2) + j * 64 + lane;
      int row = ci >> 3, c = ci & 7, sc = c ^ (row & 7);
      gload_lds16(Ab + (long)row * lda + k0 + sc * 8, &As[(wid * (BM * 2) + j * 64) * 8]);
    }
#pragma unroll
    for (int j = 0; j < 4; j++) {
      int ci = wid * 256 + j * 64 + lane;
      int row = ci >> 3, c = ci & 7, sc = c ^ (row & 7);
      gload_lds16(Bb + (long)row * ldb + k0 + sc * 8, &Bs[(wid * 256 + j * 64) * 8]);
    }
    __syncthreads();
#pragma unroll
    for (int ks = 0; ks < 2; ks++) {
      bf16x8 af[4], bfr[FN];
#pragma unroll
      for (int fm = 0; fm < 4; fm++) {
        int r = wr * 64 + fm * 16 + (lane & 15);
        int c = (ks * 4 + kq) ^ (r & 7);
        af[fm] = *reinterpret_cast<const bf16x8*>(&As[r * 64 + c * 8]);
      }
#pragma unroll
      for (int fn = 0; fn < FN; fn++) {
        int r = wc * (16 * FN) + fn * 16 + (lane & 15);
        int c = (ks * 4 + kq) ^ (r & 7);
        bfr[fn] = *reinterpret_cast<const bf16x8*>(&Bs[r * 64 + c * 8]);
      }
#pragma unroll
      for (int fm = 0; fm < 4; fm++)
#pragma unroll
        for (int fn = 0; fn < FN; fn++)
          acc[fm][fn] = __builtin_amdgcn_mfma_f32_16x16x32_bf16(af[fm], bfr[fn],
                                                                acc[fm][fn], 0, 0, 0);
    }
  }

  if constexpr (OUTMODE == 2) {
    __syncthreads();
    char* Cb = reinterpret_cast<char*>(smem);
#pragma unroll
    for (int fm = 0; fm < 4; fm++)
#pragma unroll
      for (int fn = 0; fn < FN; fn++) {
        int c = wc * 64 + fn * 16 + (lane & 15);
        int gcol = blockIdx.x * 128 + c;
        float bv = bias[gcol];
#pragma unroll
        for (int r4 = 0; r4 < 4; r4++) {
          int r = wr * 64 + fm * 16 + kq * 4 + r4;
          float v = fmaxf(acc[fm][fn][r4] + bv, 0.f);  // relu
          *reinterpret_cast<__bf16*>(Cb + r * 256 + (((c >> 3) ^ (r & 7)) << 4) +
                                     ((c & 7) << 1)) = (__bf16)v;
        }
      }
    __syncthreads();
    long bbq = (blockIdx.y * 128) >> 11;
    int srow0 = (blockIdx.y * 128) & 2047;
    if (blockIdx.x < 8) {
      int r = t >> 1, half = t & 1;
      int gcol = blockIdx.x * 128 + half * 64;
      __bf16* dst;
      if (gcol < 512)
        dst = outB + ((bbq * 8 + (gcol >> 6)) * 2048 + srow0 + r) * 64;
      else
        dst = outK + ((bbq * 8 + ((gcol - 512) >> 6)) * 2048 + srow0 + r) * 64;
      const char* srcrow = Cb + r * 256;
#pragma unroll
      for (int j = 0; j < 8; j++) {
        bf16x8 vv = *reinterpret_cast<const bf16x8*>(
            srcrow + ((((half * 8 + j) ^ (r & 7))) << 4));
        *reinterpret_cast<bf16x8*>(dst + j * 8) = vv;
      }
    } else {
      int d = t & 63, seg = t >> 6;
      int srow = srow0 + seg * 32;
#pragma unroll
      for (int h2 = 0; h2 < 2; h2++) {
        int c = h2 * 64 + d;
        int h = (blockIdx.x * 128 - 1024 + h2 * 64) >> 6;
        __bf16* dst = outVt + (bbq * 8 + h) * 131072 + (srow >> 5) * 2048 + d * 32;
        bf16x8 wv8[4];
#pragma unroll
        for (int i = 0; i < 32; i++) {
          int r = seg * 32 + i;
          __bf16 val = *reinterpret_cast<const __bf16*>(
              Cb + r * 256 + (((c >> 3) ^ (r & 7)) << 4) + ((c & 7) << 1));
          wv8[i >> 3][i & 7] = val;
        }
#pragma unroll
        for (int i4 = 0; i4 < 4; i4++)
          *reinterpret_cast<bf16x8*>(dst + i4 * 8) = wv8[i4];
      }
    }
    return;
  } else {
    long gr0 = (long)blockIdx.y * BM + wr * 64;
    long gc0 = (long)blockIdx.x * 128 + wc * (16 * FN);
#pragma unroll
    for (int fm = 0; fm < 4; fm++)
#pragma unroll
      for (int fn = 0; fn < FN; fn++) {
        int col = (int)gc0 + fn * 16 + (lane & 15);
        long rbase = gr0 + fm * 16 + kq * 4;
        float bv = bias ? bias[col] : 0.f;
#pragma unroll
        for (int r4 = 0; r4 < 4; r4++) {
          long grow = rbase + r4;
          float v = acc[fm][fn][r4] + bv;
          if (HASRES) v += res[grow * ldc + col];
          if (ACT == 1) v = fmaxf(v, 0.f);
          if (ACT == 2) v = 0.5f * v * (1.f + erff(v * 0.70710678118f));
          if (OUTMODE == 0) {
            outF[grow * ldc + col] = v;
          } else {
            outB[grow * ldc + col] = (__bf16)v;
          }
        }
      }
  }
}

// ---------------- Gram partials: per (head, 64-k chunk) G-part + kbar-part ----
__global__ __launch_bounds__(256) void gram_kernel(const __bf16* __restrict__ Kh,
                                                   float* __restrict__ gpart,
                                                   float* __restrict__ kpart) {
  int head = blockIdx.x >> 5, chunk = blockIdx.x & 31;
  __shared__ __align__(16) __bf16 kl[64 * 64];
  int t = threadIdx.x;
  const __bf16* src = Kh + ((long)head * 2048 + chunk * 64) * 64;
#pragma unroll
  for (int i = 0; i < 2; i++) {
    int e = (i * 256 + t) * 8;
    *reinterpret_cast<short8*>(&kl[e]) = *reinterpret_cast<const short8*>(&src[e]);
  }
  __syncthreads();
  int d1 = t & 63, g = t >> 6;
  float acc[16];
#pragma unroll
  for (int i = 0; i < 16; i++) acc[i] = 0.f;
  float kb = 0.f;
  for (int r = 0; r < 64; r++) {
    float k1 = (float)kl[r * 64 + d1];
    kb += k1;
    bf16x8 a = *reinterpret_cast<const bf16x8*>(&kl[r * 64 + g * 16]);
    bf16x8 b = *reinterpret_cast<const bf16x8*>(&kl[r * 64 + g * 16 + 8]);
#pragma unroll
    for (int i = 0; i < 8; i++) acc[i] += k1 * (float)a[i];
#pragma unroll
    for (int i = 0; i < 8; i++) acc[8 + i] += k1 * (float)b[i];
  }
  float* gp = gpart + ((long)chunk * 16 + head) * 4096 + d1 * 64 + g * 16;
#pragma unroll
  for (int i = 0; i < 16; i++) gp[i] = acc[i];
  if (g == 0) kpart[(chunk * 16 + head) * 64 + d1] = kb;
}

// ---------------- reduce Gram partials -> G (fp32), kbar ----------------
__global__ __launch_bounds__(256) void greduce_kernel(const float* __restrict__ gpart,
                                                      const float* __restrict__ kpart,
                                                      float* __restrict__ G,
                                                      float* __restrict__ kbar) {
  int idx = blockIdx.x * 256 + threadIdx.x;
  if (idx < 65536) {
    int head = idx >> 12, e = idx & 4095;
    float s = 0.f;
#pragma unroll 4
    for (int c = 0; c < 32; c++) s += gpart[((long)c * 16 + head) * 4096 + e];
    G[idx] = s;
  } else if (idx < 66560) {
    int k = idx - 65536;
    int head = k >> 6, d = k & 63;
    float s = 0.f;
#pragma unroll 4
    for (int c = 0; c < 32; c++) s += kpart[(c * 16 + head) * 64 + d];
    kbar[k] = s * (1.f / 2048.f);
  }
}

// ---------------- per-row stats: mu = q.kbar ; s2 = q^T G q -> (mu, rsqrt) ----
__global__ __launch_bounds__(256, 4) void stats_kernel(const __bf16* __restrict__ Qh,
                                                       const float* __restrict__ G,
                                                       const float* __restrict__ kbar,
                                                       float2* __restrict__ stats) {
  int head = blockIdx.x >> 5, sub = blockIdx.x & 31;
  __shared__ float Gl[4096];
  __shared__ float kbl[64];
  __shared__ __align__(16) float qlf[64 * 68];
  int t = threadIdx.x;
  const float* Gsrc = G + head * 4096;
#pragma unroll
  for (int i = 0; i < 4; i++) {
    int e = (i * 256 + t) * 4;
    *reinterpret_cast<float4*>(&Gl[e]) = *reinterpret_cast<const float4*>(&Gsrc[e]);
  }
  if (t < 16)
    *reinterpret_cast<float4*>(&kbl[t * 4]) =
        *reinterpret_cast<const float4*>(&kbar[head * 64 + t * 4]);
  const __bf16* qsrc = Qh + ((long)head * 2048 + sub * 64) * 64;
#pragma unroll
  for (int i = 0; i < 2; i++) {
    int e = (i * 256 + t) * 8;
    bf16x8 v = *reinterpret_cast<const bf16x8*>(&qsrc[e]);
    int row = e >> 6, col = e & 63;
    float* dst = &qlf[row * 68 + col];
#pragma unroll
    for (int j = 0; j < 8; j++) dst[j] = (float)v[j];
  }
  __syncthreads();
  int qrow = t >> 2, qt = t & 3;
  const float* qr = &qlf[qrow * 68];
  float mup = 0.f, s2p = 0.f;
#pragma unroll
  for (int i = 0; i < 16; i++) {
    int d1 = qt * 16 + i;
    const float* Gr = &Gl[d1 * 64];
    float acc = 0.f;
#pragma unroll
    for (int j = 0; j < 64; j++) acc += Gr[j] * qr[j];
    float q1 = qr[d1];
    s2p += q1 * acc;
    mup += q1 * kbl[d1];
  }
  mup += __shfl_xor(mup, 1); mup += __shfl_xor(mup, 2);
  s2p += __shfl_xor(s2p, 1); s2p += __shfl_xor(s2p, 2);
  if (qt == 0) {
    float mu = mup;
    float var = (s2p - 2048.f * mu * mu) * (1.f / 2047.f);
    stats[(head << 11) + sub * 64 + qrow] = make_float2(mu, rsqrtf(var + 1e-5f));
  }
}

// ---------------- attn8: 8-wave k-split GEMM-shaped attention ----------------
// Block = 64 q-rows of one head, 512 threads (8 waves). Wave w: q-rows
// (w&3)*16 + ln, k-half (w>>2)*1024 (8 tiles of 128). Z joined across wave
// pairs (w, w^4) via red2; hv partials joined via LDS (unioned onto dead Ks).
// 512 blocks x 8 waves, LDS ~65KB -> 2 blocks/CU = 16 waves/CU (vs attn6's 8).
__global__ __launch_bounds__(512, 4) void attn8_kernel(
    const __bf16* __restrict__ Qh, const __bf16* __restrict__ Kh,
    const __bf16* __restrict__ Vp, const float2* __restrict__ stats,
    float* __restrict__ sco, __bf16* __restrict__ hv) {
  __shared__ __align__(16) __bf16 Ks[2][128 * 64];    // per k-half, 16 KB each
  __shared__ __align__(16) __bf16 Vs[2][4 * 64 * 32]; // per k-half, 16 KB each
  __shared__ float red2[8][16];
  float* hvp = reinterpret_cast<float*>(Ks);          // union: [4][16][68] fp32

  int bid = blockIdx.x;                  // 512 blocks
  int xcd = bid & 7, j = bid >> 3;
  int head = xcd * 2 + (j >> 5);
  int qt = j & 31;
  int bb = head >> 3, hh = head & 7;
  int q0 = qt * 64;

  int t = threadIdx.x, lane = t & 63, wv = t >> 6;   // 8 waves
  int g = wv & 3, kh = wv >> 2;
  int cg = lane >> 4, ln = lane & 15;
  int sw7 = ln & 7, sw3 = ln & 3;

  int qrow = q0 + g * 16 + ln;
  const __bf16* Qr = Qh + ((long)head * 2048 + qrow) * 64;
  bf16x8 qf0 = *reinterpret_cast<const bf16x8*>(Qr + cg * 8);
  bf16x8 qf1 = *reinterpret_cast<const bf16x8*>(Qr + 32 + cg * 8);
  float2 st = stats[(head << 11) + qrow];
  float mu = st.x, rs = st.y;

  const __bf16* Kbase = Kh + (long)head * 131072 + kh * 65536;
  const __bf16* Vbase = Vp + (long)head * 131072 + kh * 65536;

  // ---- pass 1: Z partial over this wave's k-half ----
  float Z = 0.f;
  for (int kt = 0; kt < 8; kt++) {
    __syncthreads();
    const __bf16* Kt = Kbase + kt * 8192;
#pragma unroll
    for (int jj = 0; jj < 4; jj++) {
      int ci = g * 256 + jj * 64 + lane;       // 1024 chunks per kh-group
      int row = ci >> 3, c = ci & 7, sc = c ^ (row & 7);
      gload_lds16(Kt + row * 64 + sc * 8, &Ks[kh][(g * 256 + jj * 64) * 8]);
    }
    __syncthreads();
#pragma unroll
    for (int sl = 0; sl < 8; sl++) {
      const __bf16* kr = &Ks[kh][(sl * 16 + ln) * 64];
      bf16x8 a0 = *reinterpret_cast<const bf16x8*>(kr + ((cg ^ sw7) * 8));
      bf16x8 a1 = *reinterpret_cast<const bf16x8*>(kr + (((cg + 4) ^ sw7) * 8));
      f32x4 d = (f32x4){0.f, 0.f, 0.f, 0.f};
      d = __builtin_amdgcn_mfma_f32_16x16x32_bf16(a0, qf0, d, 0, 0, 0);
      d = __builtin_amdgcn_mfma_f32_16x16x32_bf16(a1, qf1, d, 0, 0, 0);
      Z += (1.f + __sinf(1.25f * (d[0] - mu) * rs));
      Z += (1.f + __sinf(1.25f * (d[1] - mu) * rs));
      Z += (1.f + __sinf(1.25f * (d[2] - mu) * rs));
      Z += (1.f + __sinf(1.25f * (d[3] - mu) * rs));
    }
  }
  Z += __shfl_xor(Z, 16);
  Z += __shfl_xor(Z, 32);
  if (lane < 16) red2[wv][ln] = Z;
  __syncthreads();
  float invZ = 1.f / (red2[g][ln] + red2[g + 4][ln]);

  // ---- pass 2: scores + PV over this wave's k-half ----
  f32x4 hacc[4];
#pragma unroll
  for (int dt = 0; dt < 4; dt++) hacc[dt] = (f32x4){0.f, 0.f, 0.f, 0.f};
  float* srow = sco + ((long)head * 2048 + qrow) * 2048 + kh * 1024;

  for (int kt = 0; kt < 8; kt++) {
    __syncthreads();
    const __bf16* Kt = Kbase + kt * 8192;
    const __bf16* Vt = Vbase + kt * 8192;
#pragma unroll
    for (int jj = 0; jj < 4; jj++) {
      int ci = g * 256 + jj * 64 + lane;
      int rowk = ci >> 3, ck = ci & 7, sck = ck ^ (rowk & 7);
      gload_lds16(Kt + rowk * 64 + sck * 8, &Ks[kh][(g * 256 + jj * 64) * 8]);
      int rowv = ci >> 2, cv = ci & 3, scv = cv ^ (rowv & 3);
      gload_lds16(Vt + rowv * 32 + scv * 8, &Vs[kh][(g * 256 + jj * 64) * 8]);
    }
    __syncthreads();
#pragma unroll
    for (int w = 0; w < 4; w++) {
      const __bf16* kr0 = &Ks[kh][(w * 32 + ln) * 64];
      const __bf16* kr1 = &Ks[kh][(w * 32 + 16 + ln) * 64];
      f32x4 d0 = (f32x4){0.f, 0.f, 0.f, 0.f}, d1 = (f32x4){0.f, 0.f, 0.f, 0.f};
      d0 = __builtin_amdgcn_mfma_f32_16x16x32_bf16(
          *reinterpret_cast<const bf16x8*>(kr0 + ((cg ^ sw7) * 8)), qf0, d0, 0, 0, 0);
      d0 = __builtin_amdgcn_mfma_f32_16x16x32_bf16(
          *reinterpret_cast<const bf16x8*>(kr0 + (((cg + 4) ^ sw7) * 8)), qf1, d0, 0, 0, 0);
      d1 = __builtin_amdgcn_mfma_f32_16x16x32_bf16(
          *reinterpret_cast<const bf16x8*>(kr1 + ((cg ^ sw7) * 8)), qf0, d1, 0, 0, 0);
      d1 = __builtin_amdgcn_mfma_f32_16x16x32_bf16(
          *reinterpret_cast<const bf16x8*>(kr1 + (((cg + 4) ^ sw7) * 8)), qf1, d1, 0, 0, 0);
      float p0 = 1.f + __sinf(1.25f * (d0[0] - mu) * rs);
      float p1 = 1.f + __sinf(1.25f * (d0[1] - mu) * rs);
      float p2 = 1.f + __sinf(1.25f * (d0[2] - mu) * rs);
      float p3 = 1.f + __sinf(1.25f * (d0[3] - mu) * rs);
      float p4 = 1.f + __sinf(1.25f * (d1[0] - mu) * rs);
      float p5 = 1.f + __sinf(1.25f * (d1[1] - mu) * rs);
      float p6 = 1.f + __sinf(1.25f * (d1[2] - mu) * rs);
      float p7 = 1.f + __sinf(1.25f * (d1[3] - mu) * rs);
      f32x4 o0 = (f32x4){p0 * invZ, p1 * invZ, p2 * invZ, p3 * invZ};
      f32x4 o1 = (f32x4){p4 * invZ, p5 * invZ, p6 * invZ, p7 * invZ};
      *reinterpret_cast<f32x4*>(srow + kt * 128 + w * 32 + cg * 4) = o0;
      *reinterpret_cast<f32x4*>(srow + kt * 128 + w * 32 + 16 + cg * 4) = o1;
      bf16x2 c0, c1, c2, c3;
      c0[0] = (__bf16)p0; c0[1] = (__bf16)p1;
      c1[0] = (__bf16)p2; c1[1] = (__bf16)p3;
      c2[0] = (__bf16)p4; c2[1] = (__bf16)p5;
      c3[0] = (__bf16)p6; c3[1] = (__bf16)p7;
      u32x4 pk = (u32x4){__builtin_bit_cast(unsigned, c0), __builtin_bit_cast(unsigned, c1),
                         __builtin_bit_cast(unsigned, c2), __builtin_bit_cast(unsigned, c3)};
      bf16x8 pf = __builtin_bit_cast(bf16x8, pk);
#pragma unroll
      for (int dt = 0; dt < 4; dt++) {
        const char* vr = reinterpret_cast<const char*>(Vs[kh]) + (w * 64 + dt * 16 + ln) * 64;
        int b0 = ((((cg >> 1) ^ sw3)) << 4) + ((cg & 1) << 3);
        int b1 = (((((cg >> 1) + 2) ^ sw3)) << 4) + ((cg & 1) << 3);
        u32x2 vlo = *reinterpret_cast<const u32x2*>(vr + b0);
        u32x2 vhi = *reinterpret_cast<const u32x2*>(vr + b1);
        u32x4 vpk = (u32x4){vlo[0], vlo[1], vhi[0], vhi[1]};
        bf16x8 vf = __builtin_bit_cast(bf16x8, vpk);
        hacc[dt] = __builtin_amdgcn_mfma_f32_16x16x32_bf16(vf, pf, hacc[dt], 0, 0, 0);
      }
    }
  }

  // ---- hv join: kh1 partials via LDS (unioned on Ks), kh0 adds + stores ----
  __syncthreads();  // all Ks/Vs reads done before union overwrite
  if (kh == 1) {
#pragma unroll
    for (int dt = 0; dt < 4; dt++)
      *reinterpret_cast<f32x4*>(hvp + ((g * 16 + ln) * 68 + dt * 16 + cg * 4)) = hacc[dt];
  }
  __syncthreads();
  if (kh == 0) {
    __bf16* hq = hv + ((long)(bb * 2048) + qrow) * 512 + hh * 64;
#pragma unroll
    for (int dt = 0; dt < 4; dt++) {
      f32x4 o = *reinterpret_cast<const f32x4*>(hvp + ((g * 16 + ln) * 68 + dt * 16 + cg * 4));
      bf16x2 w0, w1;
      w0[0] = (__bf16)((hacc[dt][0] + o[0]) * invZ);
      w0[1] = (__bf16)((hacc[dt][1] + o[1]) * invZ);
      w1[0] = (__bf16)((hacc[dt][2] + o[2]) * invZ);
      w1[1] = (__bf16)((hacc[dt][3] + o[3]) * invZ);
      *reinterpret_cast<bf16x2*>(hq + dt * 16 + cg * 4) = w0;
      *reinterpret_cast<bf16x2*>(hq + dt * 16 + cg * 4 + 2) = w1;
    }
  }
}

// ---------------- launch ----------------
extern "C" void kernel_launch(void* const* d_in, const int* in_sizes, int n_in,
                              void* d_out, int out_size, void* d_ws, size_t ws_size,
                              hipStream_t stream) {
  const float* x = (const float*)d_in[0];
  const float* norm_w = (const float*)d_in[1];
  const float* norm_b = (const float*)d_in[2];
  const float* qvk_w = (const float*)d_in[3];
  const float* qvk_b = (const float*)d_in[4];
  const float* concat_w = (const float*)d_in[5];
  const float* concat_b = (const float*)d_in[6];
  const float* mlp_norm_w = (const float*)d_in[7];
  const float* mlp_norm_b = (const float*)d_in[8];
  const float* mlp1_w = (const float*)d_in[9];
  const float* mlp1_b = (const float*)d_in[10];
  const float* mlp2_w = (const float*)d_in[11];
  const float* mlp2_b = (const float*)d_in[12];

  char* ws = (char*)d_ws;
  __bf16* qvk_wT = (__bf16*)(ws + 0);          // 1536x512
  __bf16* concat_wT = (__bf16*)(ws + 1572864); // 512x512
  __bf16* mlp1_wT = (__bf16*)(ws + 2097152);   // 1024x512
  __bf16* mlp2_wT = (__bf16*)(ws + 3145728);   // 512x1024
  __bf16* xn = (__bf16*)(ws + 4194304);        // 4096x512
  __bf16* Qh = (__bf16*)(ws + 8388608);        // (16 heads)x2048x64
  __bf16* Kh = (__bf16*)(ws + 12582912);       // (16 heads)x2048x64
  __bf16* Vp = (__bf16*)(ws + 16777216);       // (16 heads) 32-k panels
  __bf16* hv = (__bf16*)(ws + 20971520);       // 4096x512
  float* gpart = (float*)(ws + 25165824);      // 8MB (later reused as attout)
  float* attout = (float*)(ws + 25165824);     // 4096x512 fp32
  float* kpart = (float*)(ws + 33554432);      // 128KB
  float* G = (float*)(ws + 33685504);          // 256KB
  float* kbar = (float*)(ws + 33947648);       // 4KB
  float2* stats = (float2*)(ws + 33951744);    // 256KB
  __bf16* a_b = (__bf16*)(ws + 33554432);      // 4096x512 (after attn8)
  __bf16* h_b = (__bf16*)(ws + 37748736);      // 4096x1024

  float* out0 = (float*)d_out;
  float* sco = out0 + 2097152;  // scores (B,H,S,S) fp32

  // prep: weight transpose (blocks 0-511) + first LN (512-4607)
  prep_kernel<<<4608, 256, 0, stream>>>(qvk_w, concat_w, mlp1_w, mlp2_w,
                                        qvk_wT, concat_wT, mlp1_wT, mlp2_wT,
                                        x, norm_w, norm_b, xn);

  // qkv = relu(xn @ qvk_w + b); LDS-staged epilogue -> Qh/Kh/Vp
  gemm_kernel<1, 2, false, 128><<<dim3(12, 32), 256, 0, stream>>>(
      xn, qvk_wT, qvk_b, nullptr, nullptr, Qh, Kh, Vp, 512, 512, 1536, 512);

  // per-head Gram + kbar -> per-row stats
  gram_kernel<<<512, 256, 0, stream>>>(Kh, gpart, kpart);
  greduce_kernel<<<260, 256, 0, stream>>>(gpart, kpart, G, kbar);
  stats_kernel<<<512, 256, 0, stream>>>(Qh, G, kbar, stats);

  // fused attention (scores -> out1, hv bf16), 8-wave k-split
  attn8_kernel<<<512, 512, 0, stream>>>(Qh, Kh, Vp, stats, sco, hv);

  // attout = hv @ concat_w + b + x (fp32); BM=64 -> 256 blocks
  gemm_kernel<0, 0, true, 64><<<dim3(4, 64), 256, 0, stream>>>(
      hv, concat_wT, concat_b, x, attout, nullptr, nullptr, nullptr, 512, 512, 512, 512);

  ln_kernel<<<4096, 256, 0, stream>>>(attout, mlp_norm_w, mlp_norm_b, a_b);

  // h = gelu(a @ mlp1_w + b); BM=64 -> 512 blocks
  gemm_kernel<2, 1, false, 64><<<dim3(8, 64), 256, 0, stream>>>(
      a_b, mlp1_wT, mlp1_b, nullptr, nullptr, h_b, nullptr, nullptr, 512, 512, 1024, 512);

  // out0 = h @ mlp2_w + b + attout; BM=64 -> 256 blocks
  gemm_kernel<0, 0, true, 64><<<dim3(4, 64), 256, 0, stream>>>(
      h_b, mlp2_wT, mlp2_b, attout, out0, nullptr, nullptr, nullptr, 1024, 1024, 512, 1024);
}